// Round 1
// baseline (333.257 us; speedup 1.0000x reference)
//
#include <hip/hip_runtime.h>
#include <math.h>

#define BB 4
#define CC 64
#define OO 64
#define HH 128
#define WWD 128
#define HWP (HH*WWD)   // 16384

// ---------------------------------------------------------------------------
// Kernel 1: transpose W[o][c][3][3] -> Wt[k][c][o] for coalesced LDS staging
// grid: 288 blocks x 256 threads = 73728 = 2 * 64*64*9
// ---------------------------------------------------------------------------
__global__ __launch_bounds__(256) void wtrans_kernel(
    const float* __restrict__ W1, const float* __restrict__ W2,
    float* __restrict__ Wt1, float* __restrict__ Wt2)
{
    int idx = blockIdx.x * 256 + threadIdx.x;
    const int n = OO * CC * 9;           // 36864
    const float* src;
    float* dst;
    if (idx >= n) { src = W2; dst = Wt2; idx -= n; }
    else          { src = W1; dst = Wt1; }
    // dst index = (k*64 + c)*64 + o
    int o = idx & 63;
    int c = (idx >> 6) & 63;
    int k = idx >> 12;
    dst[idx] = src[(o * CC + c) * 9 + k];
}

// ---------------------------------------------------------------------------
// Kernel 2: offsets conv: rf = lo + (hi-lo)*sigmoid(conv3x3(x, w_off)+b_off)
// grid: B*HW/64 = 1024 blocks x 256 threads.
// Block = (batch b, 64 contiguous pixels in one row). Threads: t&63 = pixel,
// t>>6 = c-quarter (16 channels each); LDS reduce over the 4 partials.
// ---------------------------------------------------------------------------
__global__ __launch_bounds__(256) void offs_kernel(
    const float* __restrict__ xin, const float* __restrict__ woff,
    const float* __restrict__ boff, const int* __restrict__ lo_p,
    const int* __restrict__ hi_p,
    float* __restrict__ rfH, float* __restrict__ rfW)
{
    __shared__ float sw[2 * CC * 9];     // 4.5 KB
    __shared__ float red[2][4][64];      // 2 KB
    int t = threadIdx.x;
    for (int i = t; i < 2 * CC * 9; i += 256) sw[i] = woff[i];

    int blk  = blockIdx.x;       // 0..1023
    int b    = blk >> 8;
    int tile = blk & 255;
    int p0   = tile * 64;
    int y    = p0 >> 7;          // row (pixels are one row segment)
    int xb   = p0 & 127;
    int p    = t & 63;
    int cq   = t >> 6;
    int xx0  = xb + p;

    __syncthreads();

    const float* xb_ptr = xin + (size_t)b * CC * HWP;
    float a0 = 0.f, a1 = 0.f;
    for (int c = cq * 16; c < cq * 16 + 16; ++c) {
        const float* xc = xb_ptr + c * HWP;
        const float* w0 = sw + (0 * CC + c) * 9;
        const float* w1 = sw + (1 * CC + c) * 9;
#pragma unroll
        for (int ky = 0; ky < 3; ++ky) {
            int yy = y + ky - 1;
            bool yok = (yy >= 0) && (yy < HH);
#pragma unroll
            for (int kx = 0; kx < 3; ++kx) {
                int xx = xx0 + kx - 1;
                float v = 0.f;
                if (yok && xx >= 0 && xx < WWD) v = xc[yy * WWD + xx];
                a0 = fmaf(v, w0[ky * 3 + kx], a0);
                a1 = fmaf(v, w1[ky * 3 + kx], a1);
            }
        }
    }
    red[0][cq][p] = a0;
    red[1][cq][p] = a1;
    __syncthreads();
    if (t < 64) {
        float lo = (float)lo_p[0];
        float hi = (float)hi_p[0];
        float s0 = red[0][0][t] + red[0][1][t] + red[0][2][t] + red[0][3][t] + boff[0];
        float s1 = red[1][0][t] + red[1][1][t] + red[1][2][t] + red[1][3][t] + boff[1];
        float g0 = 1.f / (1.f + expf(-s0));
        float g1 = 1.f / (1.f + expf(-s1));
        rfH[b * HWP + p0 + t] = lo + (hi - lo) * g0;
        rfW[b * HWP + p0 + t] = lo + (hi - lo) * g1;
    }
}

// ---------------------------------------------------------------------------
// Kernel 3: main arconv.
// grid: B*HW/64 = 1024 blocks x 256 threads.
// Block = (batch b, 64-pixel row segment, all 64 output channels).
// Per tap k (9 taps): fill sS[c][p] via bilinear gather, stage sW[c][o],
// then 4x4-microtile fp32 GEMM (thread -> 4 o x 4 p).
// mode 1: out = relu(acc + bias). mode 2: out = resid + acc + bias.
// ---------------------------------------------------------------------------
__global__ __launch_bounds__(256) void arconv_kernel(
    const float* __restrict__ xin,    // [B,C,H,W] input features
    const float* __restrict__ Wt,     // [9][C][O] transposed weights
    const float* __restrict__ bias,   // [O]
    const float* __restrict__ rfH, const float* __restrict__ rfW,
    const float* __restrict__ resid,  // original x (mode 2) or nullptr
    float* __restrict__ out, int mode)
{
    __shared__ float sW[CC * OO];     // 16 KB  [c][o]
    __shared__ float sS[CC * 64];     // 16 KB  [c][p]

    int t    = threadIdx.x;
    int blk  = blockIdx.x;
    int b    = blk >> 8;
    int tile = blk & 255;
    int p0   = tile * 64;
    int y    = p0 >> 7;
    int xb   = p0 & 127;

    int pl = t & 63;            // sampling pixel lane
    int cq = t >> 6;            // c quarter for sampling
    int po = (t & 15) * 4;      // GEMM: 4 pixels
    int oo = (t >> 4) * 4;      // GEMM: 4 out channels

    float acc[4][4] = {};

    int pix   = p0 + pl;
    float rh  = rfH[b * HWP + pix] * 0.5f;
    float rw  = rfW[b * HWP + pix] * 0.5f;
    float fy  = (float)y;
    float fx  = (float)(xb + pl);
    const float* xbase = xin + (size_t)b * CC * HWP;

    for (int k = 0; k < 9; ++k) {
        float dy = (float)(k / 3 - 1);
        float dx = (float)(k % 3 - 1);
        float ys = fy + dy * rh;
        float xs = fx + dx * rw;
        float y0f = floorf(ys), x0f = floorf(xs);
        float ty = ys - y0f, tx = xs - x0f;
        int iy0 = min(max((int)y0f, 0), HH - 1);
        int iy1 = min(iy0 + 1, HH - 1);
        int ix0 = min(max((int)x0f, 0), WWD - 1);
        int ix1 = min(ix0 + 1, WWD - 1);
        float w00 = (1.f - ty) * (1.f - tx);
        float w01 = (1.f - ty) * tx;
        float w10 = ty * (1.f - tx);
        float w11 = ty * tx;
        int o00 = iy0 * WWD + ix0, o01 = iy0 * WWD + ix1;
        int o10 = iy1 * WWD + ix0, o11 = iy1 * WWD + ix1;

        __syncthreads();   // previous tap's sS/sW fully consumed

        // stage sW (coalesced float4 from pre-transposed Wt)
        {
            const float4* src = (const float4*)(Wt + k * CC * OO);
            float4* dstv = (float4*)sW;
#pragma unroll
            for (int i = 0; i < 4; ++i) {
                int lin = t + 256 * i;
                dstv[lin] = src[lin];
            }
        }
        // fill sS: this thread samples pixel pl for 16 channels
        {
            const float* xc = xbase + cq * 16 * HWP;
#pragma unroll 4
            for (int i = 0; i < 16; ++i) {
                float v00 = xc[o00], v01 = xc[o01];
                float v10 = xc[o10], v11 = xc[o11];
                float s = w00 * v00 + w01 * v01 + w10 * v10 + w11 * v11;
                sS[(cq * 16 + i) * 64 + pl] = s;
                xc += HWP;
            }
        }
        __syncthreads();

        // GEMM: acc[o][p] += sW[c][oo..+3] * sS[c][po..+3]
#pragma unroll 4
        for (int c = 0; c < CC; ++c) {
            float4 w4 = *(const float4*)&sW[c * OO + oo];
            float4 s4 = *(const float4*)&sS[c * 64 + po];
            acc[0][0] = fmaf(w4.x, s4.x, acc[0][0]);
            acc[0][1] = fmaf(w4.x, s4.y, acc[0][1]);
            acc[0][2] = fmaf(w4.x, s4.z, acc[0][2]);
            acc[0][3] = fmaf(w4.x, s4.w, acc[0][3]);
            acc[1][0] = fmaf(w4.y, s4.x, acc[1][0]);
            acc[1][1] = fmaf(w4.y, s4.y, acc[1][1]);
            acc[1][2] = fmaf(w4.y, s4.z, acc[1][2]);
            acc[1][3] = fmaf(w4.y, s4.w, acc[1][3]);
            acc[2][0] = fmaf(w4.z, s4.x, acc[2][0]);
            acc[2][1] = fmaf(w4.z, s4.y, acc[2][1]);
            acc[2][2] = fmaf(w4.z, s4.z, acc[2][2]);
            acc[2][3] = fmaf(w4.z, s4.w, acc[2][3]);
            acc[3][0] = fmaf(w4.w, s4.x, acc[3][0]);
            acc[3][1] = fmaf(w4.w, s4.y, acc[3][1]);
            acc[3][2] = fmaf(w4.w, s4.z, acc[3][2]);
            acc[3][3] = fmaf(w4.w, s4.w, acc[3][3]);
        }
    }

    // epilogue
#pragma unroll
    for (int i = 0; i < 4; ++i) {
        int o = oo + i;
        float bv = bias[o];
        size_t base = (size_t)(b * OO + o) * HWP + p0 + po;
        float4 r;
        r.x = acc[i][0] + bv;
        r.y = acc[i][1] + bv;
        r.z = acc[i][2] + bv;
        r.w = acc[i][3] + bv;
        if (mode == 1) {
            r.x = fmaxf(r.x, 0.f);
            r.y = fmaxf(r.y, 0.f);
            r.z = fmaxf(r.z, 0.f);
            r.w = fmaxf(r.w, 0.f);
        } else {
            const float4 rs = *(const float4*)&resid[base];
            r.x += rs.x; r.y += rs.y; r.z += rs.z; r.w += rs.w;
        }
        *(float4*)&out[base] = r;
    }
}

// ---------------------------------------------------------------------------
extern "C" void kernel_launch(void* const* d_in, const int* in_sizes, int n_in,
                              void* d_out, int out_size, void* d_ws, size_t ws_size,
                              hipStream_t stream) {
    const float* x      = (const float*)d_in[0];
    const float* w_off1 = (const float*)d_in[1];
    const float* b_off1 = (const float*)d_in[2];
    const float* W1     = (const float*)d_in[3];
    const float* b1     = (const float*)d_in[4];
    const float* w_off2 = (const float*)d_in[5];
    const float* b_off2 = (const float*)d_in[6];
    const float* W2     = (const float*)d_in[7];
    const float* b2     = (const float*)d_in[8];
    const int*   lo_p   = (const int*)d_in[10];
    const int*   hi_p   = (const int*)d_in[11];
    float* outp = (float*)d_out;

    float* wsf = (float*)d_ws;
    float* rfH = wsf;                               // B*HW
    float* rfW = wsf + BB * HWP;                    // B*HW
    float* t1  = wsf + 2 * BB * HWP;                // B*C*HW
    float* Wt1 = t1 + (size_t)BB * CC * HWP;        // 36864
    float* Wt2 = Wt1 + OO * CC * 9;                 // 36864

    // 1. transpose both weight tensors
    wtrans_kernel<<<288, 256, 0, stream>>>(W1, W2, Wt1, Wt2);

    // 2. layer 1 offsets
    offs_kernel<<<1024, 256, 0, stream>>>(x, w_off1, b_off1, lo_p, hi_p, rfH, rfW);

    // 3. layer 1 arconv + relu -> t1
    arconv_kernel<<<1024, 256, 0, stream>>>(x, Wt1, b1, rfH, rfW, nullptr, t1, 1);

    // 4. layer 2 offsets (input = t1)
    offs_kernel<<<1024, 256, 0, stream>>>(t1, w_off2, b_off2, lo_p, hi_p, rfH, rfW);

    // 5. layer 2 arconv + residual -> out
    arconv_kernel<<<1024, 256, 0, stream>>>(t1, Wt2, b2, rfH, rfW, x, outp, 2);
}

// Round 3
// 319.778 us; speedup vs baseline: 1.0421x; 1.0421x over previous
//
#include <hip/hip_runtime.h>
#include <math.h>

#define BB 4
#define CC 64
#define OO 64
#define HH 128
#define WWD 128
#define HWP (HH*WWD)   // 16384

typedef short bf16x8 __attribute__((ext_vector_type(8)));
typedef float f32x4  __attribute__((ext_vector_type(4)));

__device__ __forceinline__ unsigned short bf16_rne(float f) {
    unsigned u = __float_as_uint(f);
    u += 0x7fffu + ((u >> 16) & 1u);
    return (unsigned short)(u >> 16);
}
__device__ __forceinline__ float bf16_tof(unsigned short h) {
    return __uint_as_float((unsigned)h << 16);
}

// ---------------------------------------------------------------------------
// Kernel 1: W[o][c][3][3] fp32 -> Whi/Wlo[k][o][c] bf16 (hi/lo split) for
// both layers. grid: 288 x 256 = 73728 = 2 * 64*64*9
// ---------------------------------------------------------------------------
__global__ __launch_bounds__(256) void wtrans_kernel(
    const float* __restrict__ W1, const float* __restrict__ W2,
    unsigned short* __restrict__ Wh1, unsigned short* __restrict__ Wl1,
    unsigned short* __restrict__ Wh2, unsigned short* __restrict__ Wl2)
{
    int idx = blockIdx.x * 256 + threadIdx.x;
    const int n = OO * CC * 9;           // 36864
    const float* src;
    unsigned short *dh, *dl;
    if (idx >= n) { src = W2; dh = Wh2; dl = Wl2; idx -= n; }
    else          { src = W1; dh = Wh1; dl = Wl1; }
    // dst index = (k*64 + o)*64 + c
    int c = idx & 63;
    int o = (idx >> 6) & 63;
    int k = idx >> 12;
    float w = src[(o * CC + c) * 9 + k];
    unsigned short hi = bf16_rne(w);
    unsigned short lo = bf16_rne(w - bf16_tof(hi));
    dh[idx] = hi;
    dl[idx] = lo;
}

// ---------------------------------------------------------------------------
// Kernel 2: offsets conv: rf = lo + (hi-lo)*sigmoid(conv3x3(x, w_off)+b_off)
// grid: B*HW/64 = 1024 blocks x 256 threads. (unchanged — passed twice)
// ---------------------------------------------------------------------------
__global__ __launch_bounds__(256) void offs_kernel(
    const float* __restrict__ xin, const float* __restrict__ woff,
    const float* __restrict__ boff, const int* __restrict__ lo_p,
    const int* __restrict__ hi_p,
    float* __restrict__ rfH, float* __restrict__ rfW)
{
    __shared__ float sw[2 * CC * 9];
    __shared__ float red[2][4][64];
    int t = threadIdx.x;
    for (int i = t; i < 2 * CC * 9; i += 256) sw[i] = woff[i];

    int blk  = blockIdx.x;
    int b    = blk >> 8;
    int tile = blk & 255;
    int p0   = tile * 64;
    int y    = p0 >> 7;
    int xb   = p0 & 127;
    int p    = t & 63;
    int cq   = t >> 6;
    int xx0  = xb + p;

    __syncthreads();

    const float* xb_ptr = xin + (size_t)b * CC * HWP;
    float a0 = 0.f, a1 = 0.f;
    for (int c = cq * 16; c < cq * 16 + 16; ++c) {
        const float* xc = xb_ptr + c * HWP;
        const float* w0 = sw + (0 * CC + c) * 9;
        const float* w1 = sw + (1 * CC + c) * 9;
#pragma unroll
        for (int ky = 0; ky < 3; ++ky) {
            int yy = y + ky - 1;
            bool yok = (yy >= 0) && (yy < HH);
#pragma unroll
            for (int kx = 0; kx < 3; ++kx) {
                int xx = xx0 + kx - 1;
                float v = 0.f;
                if (yok && xx >= 0 && xx < WWD) v = xc[yy * WWD + xx];
                a0 = fmaf(v, w0[ky * 3 + kx], a0);
                a1 = fmaf(v, w1[ky * 3 + kx], a1);
            }
        }
    }
    red[0][cq][p] = a0;
    red[1][cq][p] = a1;
    __syncthreads();
    if (t < 64) {
        float lo = (float)lo_p[0];
        float hi = (float)hi_p[0];
        float s0 = red[0][0][t] + red[0][1][t] + red[0][2][t] + red[0][3][t] + boff[0];
        float s1 = red[1][0][t] + red[1][1][t] + red[1][2][t] + red[1][3][t] + boff[1];
        float g0 = 1.f / (1.f + expf(-s0));
        float g1 = 1.f / (1.f + expf(-s1));
        rfH[b * HWP + p0 + t] = lo + (hi - lo) * g0;
        rfW[b * HWP + p0 + t] = lo + (hi - lo) * g1;
    }
}

// ---------------------------------------------------------------------------
// Kernel 3: main arconv, bf16-MFMA with hi/lo split (fp32-accurate).
// grid: 1024 blocks x 256 threads (4 waves).
// Per tap k: bilinear-sample sSh/sSl[p][c] (bf16 hi/lo, pad 72), stage
// sWh/sWl[o][c], then 16x16x32 bf16 MFMA, 3 products: Wh*Sh + Wl*Sh + Wh*Sl.
// Fragment layouts per m89/m120 (HW-verified for bf16):
//   A[m=lane&15][k=quad*8+j], B[k=quad*8+j][n=lane&15],
//   D: col=lane&15, row=quad*4+reg.
// mode 1: out = relu(acc + bias). mode 2: out = resid + acc + bias.
// ---------------------------------------------------------------------------
__global__ __launch_bounds__(256) void arconv_kernel(
    const float*          __restrict__ xin,   // [B,C,H,W]
    const unsigned short* __restrict__ Whi,   // [9][O][C] bf16 hi
    const unsigned short* __restrict__ Wlo,   // [9][O][C] bf16 lo
    const float*          __restrict__ bias,
    const float* __restrict__ rfH, const float* __restrict__ rfW,
    const float* __restrict__ resid,
    float* __restrict__ out, int mode)
{
    __shared__ unsigned short sWh[OO * 72];  // [o][c] padded, 9216 B each
    __shared__ unsigned short sWl[OO * 72];
    __shared__ unsigned short sSh[64 * 72];  // [p][c] padded
    __shared__ unsigned short sSl[64 * 72];

    int t    = threadIdx.x;
    int blk  = blockIdx.x;
    int b    = blk >> 8;
    int tile = blk & 255;
    int p0   = tile * 64;
    int y    = p0 >> 7;
    int xb   = p0 & 127;

    int lane = t & 63;
    int wv   = t >> 6;
    int pl   = lane;            // sampling pixel
    int cq   = wv;              // sampling c-quarter
    int nidx = lane & 15;
    int quad = lane >> 4;

    f32x4 acc[4] = {};

    int pix  = p0 + pl;
    float rh = rfH[b * HWP + pix] * 0.5f;
    float rw = rfW[b * HWP + pix] * 0.5f;
    float fy = (float)y;
    float fx = (float)(xb + pl);
    const float* xbase = xin + (size_t)b * CC * HWP + (size_t)cq * 16 * HWP;

    for (int k = 0; k < 9; ++k) {
        float dy = (float)(k / 3 - 1);
        float dx = (float)(k % 3 - 1);
        float ys = fy + dy * rh;
        float xs = fx + dx * rw;
        float y0f = floorf(ys), x0f = floorf(xs);
        float ty = ys - y0f, tx = xs - x0f;
        int iy0 = min(max((int)y0f, 0), HH - 1);
        int iy1 = min(iy0 + 1, HH - 1);
        int ix0 = min(max((int)x0f, 0), WWD - 1);
        int ix1 = min(ix0 + 1, WWD - 1);
        float w00 = (1.f - ty) * (1.f - tx);
        float w01 = (1.f - ty) * tx;
        float w10 = ty * (1.f - tx);
        float w11 = ty * tx;
        int o00 = iy0 * WWD + ix0, o01 = iy0 * WWD + ix1;
        int o10 = iy1 * WWD + ix0, o11 = iy1 * WWD + ix1;

        // weight stage loads (32 B/thread/array), issued before the barrier
        const uint4* whs = (const uint4*)(Whi + (size_t)k * OO * CC);
        const uint4* wls = (const uint4*)(Wlo + (size_t)k * OO * CC);
        uint4 wh0 = whs[t * 2];
        uint4 wh1 = whs[t * 2 + 1];
        uint4 wl0 = wls[t * 2];
        uint4 wl1 = wls[t * 2 + 1];

        // sample 16 channels for pixel pl; split into bf16 hi/lo
        union { unsigned short h[16]; uint4 q[2]; } svh, svl;
        {
            const float* xc = xbase;
#pragma unroll
            for (int i = 0; i < 16; ++i) {
                float v00 = xc[o00], v01 = xc[o01];
                float v10 = xc[o10], v11 = xc[o11];
                float s = w00 * v00 + w01 * v01 + w10 * v10 + w11 * v11;
                unsigned short hs = bf16_rne(s);
                svh.h[i] = hs;
                svl.h[i] = bf16_rne(s - bf16_tof(hs));
                xc += HWP;
            }
        }

        __syncthreads();   // previous tap's LDS fully consumed

        // write sWh/sWl: thread t -> o = t>>2, c = (t&3)*16 .. +16
        {
            unsigned short* dh = &sWh[(t >> 2) * 72 + (t & 3) * 16];
            unsigned short* dl = &sWl[(t >> 2) * 72 + (t & 3) * 16];
            *(uint4*)dh       = wh0;
            *(uint4*)(dh + 8) = wh1;
            *(uint4*)dl       = wl0;
            *(uint4*)(dl + 8) = wl1;
        }
        // write sSh/sSl: pixel pl, channels cq*16 .. +16
        {
            unsigned short* dh = &sSh[pl * 72 + cq * 16];
            unsigned short* dl = &sSl[pl * 72 + cq * 16];
            *(uint4*)dh       = svh.q[0];
            *(uint4*)(dh + 8) = svh.q[1];
            *(uint4*)dl       = svl.q[0];
            *(uint4*)(dl + 8) = svl.q[1];
        }
        __syncthreads();

        // GEMM over K=64 (2 MFMA K-steps of 32), 3-product hi/lo compensation
#pragma unroll
        for (int ks = 0; ks < 2; ++ks) {
            int boff = (wv * 16 + nidx) * 72 + quad * 8 + ks * 32;
            bf16x8 bh = *(const bf16x8*)&sSh[boff];
            bf16x8 bl = *(const bf16x8*)&sSl[boff];
#pragma unroll
            for (int mt = 0; mt < 4; ++mt) {
                int aoff = (mt * 16 + nidx) * 72 + quad * 8 + ks * 32;
                bf16x8 ah = *(const bf16x8*)&sWh[aoff];
                bf16x8 al = *(const bf16x8*)&sWl[aoff];
                acc[mt] = __builtin_amdgcn_mfma_f32_16x16x32_bf16(ah, bh, acc[mt], 0, 0, 0);
                acc[mt] = __builtin_amdgcn_mfma_f32_16x16x32_bf16(al, bh, acc[mt], 0, 0, 0);
                acc[mt] = __builtin_amdgcn_mfma_f32_16x16x32_bf16(ah, bl, acc[mt], 0, 0, 0);
            }
        }
    }

    // epilogue: o = mt*16 + quad*4 + r, px = wv*16 + nidx
    int px = wv * 16 + nidx;
#pragma unroll
    for (int mt = 0; mt < 4; ++mt) {
#pragma unroll
        for (int r = 0; r < 4; ++r) {
            int o = mt * 16 + quad * 4 + r;
            float v = acc[mt][r] + bias[o];
            size_t idx = (size_t)(b * OO + o) * HWP + p0 + px;
            if (mode == 1) v = fmaxf(v, 0.f);
            else           v += resid[idx];
            out[idx] = v;
        }
    }
}

// ---------------------------------------------------------------------------
extern "C" void kernel_launch(void* const* d_in, const int* in_sizes, int n_in,
                              void* d_out, int out_size, void* d_ws, size_t ws_size,
                              hipStream_t stream) {
    const float* x      = (const float*)d_in[0];
    const float* w_off1 = (const float*)d_in[1];
    const float* b_off1 = (const float*)d_in[2];
    const float* W1     = (const float*)d_in[3];
    const float* b1     = (const float*)d_in[4];
    const float* w_off2 = (const float*)d_in[5];
    const float* b_off2 = (const float*)d_in[6];
    const float* W2     = (const float*)d_in[7];
    const float* b2     = (const float*)d_in[8];
    const int*   lo_p   = (const int*)d_in[10];
    const int*   hi_p   = (const int*)d_in[11];
    float* outp = (float*)d_out;

    float* wsf = (float*)d_ws;
    float* rfH = wsf;                               // B*HW f32
    float* rfW = wsf + BB * HWP;                    // B*HW f32
    float* t1  = wsf + 2 * BB * HWP;                // B*C*HW f32
    unsigned short* Wh1 = (unsigned short*)(t1 + (size_t)BB * CC * HWP);
    unsigned short* Wl1 = Wh1 + OO * CC * 9;        // 36864 each
    unsigned short* Wh2 = Wl1 + OO * CC * 9;
    unsigned short* Wl2 = Wh2 + OO * CC * 9;

    // 1. transpose+split both weight tensors
    wtrans_kernel<<<288, 256, 0, stream>>>(W1, W2, Wh1, Wl1, Wh2, Wl2);

    // 2. layer 1 offsets
    offs_kernel<<<1024, 256, 0, stream>>>(x, w_off1, b_off1, lo_p, hi_p, rfH, rfW);

    // 3. layer 1 arconv + relu -> t1
    arconv_kernel<<<1024, 256, 0, stream>>>(x, Wh1, Wl1, b1, rfH, rfW, nullptr, t1, 1);

    // 4. layer 2 offsets (input = t1)
    offs_kernel<<<1024, 256, 0, stream>>>(t1, w_off2, b_off2, lo_p, hi_p, rfH, rfW);

    // 5. layer 2 arconv + residual -> out
    arconv_kernel<<<1024, 256, 0, stream>>>(t1, Wh2, Wl2, b2, rfH, rfW, x, outp, 2);
}